// Round 4
// baseline (637.284 us; speedup 1.0000x reference)
//
#include <hip/hip_runtime.h>
#include <hip/hip_bf16.h>

#define BB 4
#define NN 1024
#define DD 256
#define NHEADS 8
#define NPTS 4
#define NKSAMP 10
#define HHF 200
#define WWF 200
#define HWF (HHF*WWF)

typedef __hip_bfloat16 bf16;

__device__ __forceinline__ float ldf(const float* p, size_t i){ return p[i]; }
__device__ __forceinline__ float ldf(const bf16*  p, size_t i){ return __bfloat162float(p[i]); }

// Decide input dtype from pc_range word 0. fp32(-51.2f) == 0xC24CCCCD.
// As bf16[2] the same bytes would be 0xC24DC24D. flag: 0 = fp32, 1 = bf16.
__global__ void detect_kernel(const unsigned* __restrict__ pc_bits, int* __restrict__ flag){
    if (threadIdx.x == 0 && blockIdx.x == 0)
        *flag = (pc_bits[0] == 0xC24CCCCDu) ? 0 : 1;
}

// bev (B, C, HW) dtype T -> bevT (B, HW, C) bf16, 32x32 tiles via LDS
template<typename T, int WANT>
__global__ __launch_bounds__(256) void transpose_kernel(const T* __restrict__ bev,
                                                        bf16* __restrict__ bevT,
                                                        const int* __restrict__ flag){
    if (*flag != WANT) return;
    __shared__ bf16 tile[32][33];
    int b  = blockIdx.z;
    int c0 = blockIdx.y * 32;
    int p0 = blockIdx.x * 32;
    int tx = threadIdx.x & 31;
    int ty = threadIdx.x >> 5;   // 0..7
    const T* src = bev + (size_t)b * DD * HWF;
    #pragma unroll
    for (int i = 0; i < 4; i++){
        int c = c0 + ty + i*8;
        tile[ty + i*8][tx] = __float2bfloat16(ldf(src, (size_t)c * HWF + p0 + tx));
    }
    __syncthreads();
    bf16* dst = bevT + (size_t)b * HWF * DD;
    #pragma unroll
    for (int i = 0; i < 4; i++){
        int p = p0 + ty + i*8;
        dst[(size_t)p * DD + c0 + tx] = tile[tx][ty + i*8];
    }
}

// One block handles 4 query rows end-to-end. 256 threads. Output float32.
// TRANS=true: gather from bf16 bevT (HW, C) coalesced. Else from bev (C, HW) dtype T.
template<typename T, bool TRANS, int WANT>
__global__ __launch_bounds__(256) void monolith_kernel(
    const T* __restrict__ qe, const T* __restrict__ ctrl,
    const T* __restrict__ bev, const bf16* __restrict__ bevT,
    const T* __restrict__ pc,
    const T* __restrict__ Wq, const T* __restrict__ bq,
    const T* __restrict__ Wval, const T* __restrict__ bval,
    const T* __restrict__ Woff, const T* __restrict__ boff,
    const T* __restrict__ Wattn, const T* __restrict__ battn,
    const T* __restrict__ Wdo, const T* __restrict__ bdo,
    const T* __restrict__ Wout, const T* __restrict__ bout,
    float* __restrict__ out, const int* __restrict__ flag)
{
    if (*flag != WANT) return;
    __shared__ float qe_s[4][256];
    __shared__ float q_s[4][256];
    __shared__ float oa_s[4][96];
    __shared__ float cen_s[4][2];
    __shared__ int   sx0_s[4][32];
    __shared__ int   sy0_s[4][32];
    __shared__ float swx_s[4][32];
    __shared__ float swy_s[4][32];
    __shared__ float sww_s[4][32];
    __shared__ float ws_s[4][8];
    __shared__ float g_s[4][2048];   // 4 rows x (8 heads * 256 channels)
    __shared__ float t_s[4][256];

    const int m0  = blockIdx.x * 4;
    const int b   = m0 >> 10;               // N = 1024
    const int tid = threadIdx.x;

    // ---- load qe rows; bezier centers ----
    for (int i = tid; i < 4*256; i += 256){
        int r = i >> 8, c = i & 255;
        qe_s[r][c] = ldf(qe, (size_t)(m0 + r)*256 + c);
    }
    if (tid < 4){
        int r = tid;
        float cx[4], cy[4];
        #pragma unroll
        for (int i = 0; i < 4; i++){
            cx[i] = ldf(ctrl, (size_t)(m0+r)*8 + i*2 + 0);
            cy[i] = ldf(ctrl, (size_t)(m0+r)*8 + i*2 + 1);
        }
        float lox = ldf(pc,0), loy = ldf(pc,1);
        float spx = ldf(pc,3) - lox, spy = ldf(pc,4) - loy;
        float sx = 0.f, sy = 0.f;
        for (int k = 0; k < NKSAMP; k++){
            float t = (float)k / (float)(NKSAMP - 1);
            float u = 1.f - t;
            float c0 = u*u*u, c1 = 3.f*u*u*t, c2 = 3.f*u*t*t, c3 = t*t*t;
            float dx = c0*cx[0] + c1*cx[1] + c2*cx[2] + c3*cx[3];
            float dy = c0*cy[0] + c1*cy[1] + c2*cy[2] + c3*cy[3];
            float rx = fminf(fmaxf((dx - lox)/spx, 0.01f), 0.99f);
            float ry = fminf(fmaxf((dy - loy)/spy, 0.01f), 0.99f);
            sx += rx; sy += ry;
        }
        cen_s[r][0] = sx / (float)NKSAMP;
        cen_s[r][1] = sy / (float)NKSAMP;
    }
    __syncthreads();

    // ---- q = qe @ W_q + b_q ----
    {
        const int j = tid;
        float acc[4] = {0.f, 0.f, 0.f, 0.f};
        for (int c = 0; c < 256; c++){
            float w = ldf(Wq, (size_t)c*256 + j);
            #pragma unroll
            for (int r = 0; r < 4; r++) acc[r] += qe_s[r][c] * w;
        }
        float bias = ldf(bq, j);
        #pragma unroll
        for (int r = 0; r < 4; r++) q_s[r][j] = acc[r] + bias;
    }
    __syncthreads();

    // ---- offsets (64 cols) + attn logits (32 cols) per row ----
    for (int idx = tid; idx < 4*96; idx += 256){
        int r = idx / 96, col = idx % 96;
        float acc = 0.f;
        if (col < 64){
            for (int c = 0; c < 256; c++) acc += q_s[r][c] * ldf(Woff, (size_t)c*64 + col);
            acc += ldf(boff, col);
        } else {
            int cc = col - 64;
            for (int c = 0; c < 256; c++) acc += q_s[r][c] * ldf(Wattn, (size_t)c*32 + cc);
            acc += ldf(battn, cc);
        }
        oa_s[r][col] = acc;
    }
    __syncthreads();

    // ---- softmax per (row, head); pixel coords; valid-weight sums ----
    if (tid < 32){
        int r = tid >> 3, h = tid & 7;
        float a0 = oa_s[r][64 + h*4 + 0], a1 = oa_s[r][64 + h*4 + 1];
        float a2 = oa_s[r][64 + h*4 + 2], a3 = oa_s[r][64 + h*4 + 3];
        float mx = fmaxf(fmaxf(a0, a1), fmaxf(a2, a3));
        float e0 = __expf(a0 - mx), e1 = __expf(a1 - mx);
        float e2 = __expf(a2 - mx), e3 = __expf(a3 - mx);
        float inv = 1.f / (e0 + e1 + e2 + e3);
        float wp[4] = {e0*inv, e1*inv, e2*inv, e3*inv};
        float cxp = cen_s[r][0] * (float)WWF - 0.5f;
        float cyp = cen_s[r][1] * (float)HHF - 0.5f;
        float wsum = 0.f;
        #pragma unroll
        for (int p = 0; p < 4; p++){
            float x = cxp + oa_s[r][h*8 + p*2 + 0];
            float y = cyp + oa_s[r][h*8 + p*2 + 1];
            float fx = floorf(x), fy = floorf(y);
            int x0 = (int)fx, y0 = (int)fy;
            float wx = x - fx, wy = y - fy;
            int s = h*4 + p;
            sx0_s[r][s] = x0; sy0_s[r][s] = y0;
            swx_s[r][s] = wx; swy_s[r][s] = wy;
            sww_s[r][s] = wp[p];
            bool vx0 = (unsigned)x0 < WWF, vx1 = (unsigned)(x0+1) < WWF;
            bool vy0 = (unsigned)y0 < HHF, vy1 = (unsigned)(y0+1) < HHF;
            float w = wp[p];
            if (vy0 && vx0) wsum += w*(1.f-wx)*(1.f-wy);
            if (vy0 && vx1) wsum += w*wx*(1.f-wy);
            if (vy1 && vx0) wsum += w*(1.f-wx)*wy;
            if (vy1 && vx1) wsum += w*wx*wy;
        }
        ws_s[r][h] = wsum;
    }
    __syncthreads();

    // ---- gather: thread = channel c ----
    {
        const int c = tid;
        const bf16* baseT = bevT + (size_t)b * HWF * DD;
        const T*    baseR = bev  + (size_t)b * DD * HWF;
        for (int r = 0; r < 4; r++){
            #pragma unroll
            for (int h = 0; h < 8; h++){
                float acc = 0.f;
                #pragma unroll
                for (int p = 0; p < 4; p++){
                    int s = h*4 + p;
                    int x0 = sx0_s[r][s], y0 = sy0_s[r][s];
                    float wx = swx_s[r][s], wy = swy_s[r][s], w = sww_s[r][s];
                    float w00 = w*(1.f-wx)*(1.f-wy);
                    float w01 = w*wx*(1.f-wy);
                    float w10 = w*(1.f-wx)*wy;
                    float w11 = w*wx*wy;
                    bool vy0 = (unsigned)y0 < HHF, vy1 = (unsigned)(y0+1) < HHF;
                    bool vx0 = (unsigned)x0 < WWF, vx1 = (unsigned)(x0+1) < WWF;
                    if (vy0){
                        int rowp = y0*WWF + x0;
                        if (vx0) acc += w00 * (TRANS ? __bfloat162float(baseT[(size_t)rowp*DD + c])
                                                     : ldf(baseR, (size_t)c*HWF + rowp));
                        if (vx1) acc += w01 * (TRANS ? __bfloat162float(baseT[(size_t)(rowp+1)*DD + c])
                                                     : ldf(baseR, (size_t)c*HWF + rowp+1));
                    }
                    if (vy1){
                        int rowp = (y0+1)*WWF + x0;
                        if (vx0) acc += w10 * (TRANS ? __bfloat162float(baseT[(size_t)rowp*DD + c])
                                                     : ldf(baseR, (size_t)c*HWF + rowp));
                        if (vx1) acc += w11 * (TRANS ? __bfloat162float(baseT[(size_t)(rowp+1)*DD + c])
                                                     : ldf(baseR, (size_t)c*HWF + rowp+1));
                    }
                }
                g_s[r][h*256 + c] = acc;
            }
        }
    }
    __syncthreads();

    // ---- out_feat = g_h @ W_val[:,j] + wsum_h * b_val[j] ----
    {
        const int j = tid;
        const int h = j >> 5;      // HD = 32
        float acc[4] = {0.f, 0.f, 0.f, 0.f};
        for (int c = 0; c < 256; c++){
            float w = ldf(Wval, (size_t)c*256 + j);
            #pragma unroll
            for (int r = 0; r < 4; r++) acc[r] += g_s[r][h*256 + c] * w;
        }
        float bv = ldf(bval, j);
        #pragma unroll
        for (int r = 0; r < 4; r++) t_s[r][j] = acc[r] + ws_s[r][h] * bv;
    }
    __syncthreads();

    // ---- msda = out @ W_do + b_do + q ----
    {
        const int j = tid;
        float acc[4] = {0.f, 0.f, 0.f, 0.f};
        for (int c = 0; c < 256; c++){
            float w = ldf(Wdo, (size_t)c*256 + j);
            #pragma unroll
            for (int r = 0; r < 4; r++) acc[r] += t_s[r][c] * w;
        }
        __syncthreads();
        float bd = ldf(bdo, j);
        #pragma unroll
        for (int r = 0; r < 4; r++) t_s[r][j] = acc[r] + bd + q_s[r][j];
    }
    __syncthreads();

    // ---- final = msda @ W_out + b_out  (float32 output) ----
    {
        const int j = tid;
        float acc[4] = {0.f, 0.f, 0.f, 0.f};
        for (int c = 0; c < 256; c++){
            float w = ldf(Wout, (size_t)c*256 + j);
            #pragma unroll
            for (int r = 0; r < 4; r++) acc[r] += t_s[r][c] * w;
        }
        float bo = ldf(bout, j);
        #pragma unroll
        for (int r = 0; r < 4; r++)
            out[(size_t)(m0+r)*256 + j] = acc[r] + bo;
    }
}

template<typename T, bool TRANS, int WANT>
static void launch_monolith(void* const* d_in, const bf16* bevT, float* out,
                            const int* flag, hipStream_t stream)
{
    monolith_kernel<T, TRANS, WANT><<<dim3(BB*NN/4), 256, 0, stream>>>(
        (const T*)d_in[0], (const T*)d_in[1], (const T*)d_in[2], bevT,
        (const T*)d_in[4],
        (const T*)d_in[5], (const T*)d_in[6], (const T*)d_in[7], (const T*)d_in[8],
        (const T*)d_in[9], (const T*)d_in[10], (const T*)d_in[11], (const T*)d_in[12],
        (const T*)d_in[13], (const T*)d_in[14], (const T*)d_in[15], (const T*)d_in[16],
        out, flag);
}

extern "C" void kernel_launch(void* const* d_in, const int* in_sizes, int n_in,
                              void* d_out, int out_size, void* d_ws, size_t ws_size,
                              hipStream_t stream)
{
    (void)in_sizes; (void)n_in; (void)out_size;
    float* out = (float*)d_out;

    int*  flag = (int*)d_ws;
    bf16* bevT = (bf16*)((char*)d_ws + 64);
    const size_t needA = 64 + (size_t)BB * HWF * DD * sizeof(bf16);   // 64 + 81,920,000 B

    detect_kernel<<<1, 64, 0, stream>>>((const unsigned*)d_in[4], flag);

    if (ws_size >= needA){
        transpose_kernel<float, 0><<<dim3(HWF/32, DD/32, BB), 256, 0, stream>>>(
            (const float*)d_in[2], bevT, flag);
        transpose_kernel<bf16, 1><<<dim3(HWF/32, DD/32, BB), 256, 0, stream>>>(
            (const bf16*)d_in[2], bevT, flag);
        launch_monolith<float, true, 0>(d_in, bevT, out, flag, stream);
        launch_monolith<bf16,  true, 1>(d_in, bevT, out, flag, stream);
    } else {
        launch_monolith<float, false, 0>(d_in, bevT, out, flag, stream);
        launch_monolith<bf16,  false, 1>(d_in, bevT, out, flag, stream);
    }
}

// Round 5
// 533.055 us; speedup vs baseline: 1.1955x; 1.1955x over previous
//
#include <hip/hip_runtime.h>
#include <hip/hip_bf16.h>

#define BB 4
#define NN 1024
#define DD 256
#define NHEADS 8
#define NPTS 4
#define NKSAMP 10
#define HHF 200
#define WWF 200
#define HWF (HHF*WWF)

typedef __hip_bfloat16 bf16;

__device__ __forceinline__ float ldf(const float* p, size_t i){ return p[i]; }
__device__ __forceinline__ float ldf(const bf16*  p, size_t i){ return __bfloat162float(p[i]); }

__device__ __forceinline__ unsigned short f2bf(float f){
    unsigned u = __float_as_uint(f);
    return (unsigned short)((u + 0x7FFFu + ((u >> 16) & 1u)) >> 16);
}
__device__ __forceinline__ void load_bf16x8(const unsigned short* p, float* v){
    int4 t = *reinterpret_cast<const int4*>(p);
    unsigned q0 = (unsigned)t.x, q1 = (unsigned)t.y, q2 = (unsigned)t.z, q3 = (unsigned)t.w;
    v[0] = __uint_as_float(q0 << 16); v[1] = __uint_as_float(q0 & 0xFFFF0000u);
    v[2] = __uint_as_float(q1 << 16); v[3] = __uint_as_float(q1 & 0xFFFF0000u);
    v[4] = __uint_as_float(q2 << 16); v[5] = __uint_as_float(q2 & 0xFFFF0000u);
    v[6] = __uint_as_float(q3 << 16); v[7] = __uint_as_float(q3 & 0xFFFF0000u);
}
__device__ __forceinline__ void store_bf16x8(unsigned short* p, const float* v){
    int4 t;
    t.x = (int)((unsigned)f2bf(v[0]) | ((unsigned)f2bf(v[1]) << 16));
    t.y = (int)((unsigned)f2bf(v[2]) | ((unsigned)f2bf(v[3]) << 16));
    t.z = (int)((unsigned)f2bf(v[4]) | ((unsigned)f2bf(v[5]) << 16));
    t.w = (int)((unsigned)f2bf(v[6]) | ((unsigned)f2bf(v[7]) << 16));
    *reinterpret_cast<int4*>(p) = t;
}

// flag: 0 = fp32 inputs, 1 = bf16 inputs. fp32(-51.2f) == 0xC24CCCCD.
__global__ void detect_kernel(const unsigned* __restrict__ pc_bits, int* __restrict__ flag){
    if (threadIdx.x == 0 && blockIdx.x == 0)
        *flag = (pc_bits[0] == 0xC24CCCCDu) ? 0 : 1;
}

// bev (B, C, HW) dtype T -> bevT (B, HW, C) bf16 bits
template<typename T, int WANT>
__global__ __launch_bounds__(256) void transpose_kernel(const T* __restrict__ bev,
                                                        unsigned short* __restrict__ bevT,
                                                        const int* __restrict__ flag){
    if (*flag != WANT) return;
    __shared__ unsigned short tile[32][33];
    int b  = blockIdx.z;
    int c0 = blockIdx.y * 32;
    int p0 = blockIdx.x * 32;
    int tx = threadIdx.x & 31;
    int ty = threadIdx.x >> 5;   // 0..7
    const T* src = bev + (size_t)b * DD * HWF;
    #pragma unroll
    for (int i = 0; i < 4; i++){
        int c = c0 + ty + i*8;
        tile[ty + i*8][tx] = f2bf(ldf(src, (size_t)c * HWF + p0 + tx));
    }
    __syncthreads();
    unsigned short* dst = bevT + (size_t)b * HWF * DD;
    #pragma unroll
    for (int i = 0; i < 4; i++){
        int p = p0 + ty + i*8;
        dst[(size_t)p * DD + c0 + tx] = tile[tx][ty + i*8];
    }
}

// ---------------- tiled fp32 GEMM: C = A@B + bias (+ws*bias) (+res) ----------------
// A: M x 256 row-major (f32, or bf16-bits when ABF16), K = 256 fixed.
// B: 256 x ldb f32. tiles: 64 rows x NT cols, 256 threads = 16(ti) x 16(tj), micro 4 x NM.
template<int NT, int NM, bool ABF16, bool HEADSLICE, bool WSBIAS, bool RES, int WANT>
__global__ __launch_bounds__(256) void gemm_kernel(
    const void* __restrict__ Av, int lda,
    const float* __restrict__ B, int ldb,
    const float* __restrict__ bias,
    const float* __restrict__ wsb,
    const float* __restrict__ res,
    float* __restrict__ C, int ldc,
    const int* __restrict__ flag)
{
    if (*flag != WANT) return;
    __shared__ float As[256][68];   // A^T staged, pitch 68 (16B-aligned rows, bank-spread)
    const int n0  = blockIdx.x * NT;
    const int m0  = blockIdx.y * 64;
    const int tid = threadIdx.x;
    const int koff = HEADSLICE ? (n0 >> 5) * 256 : 0;

    if (ABF16){
        const unsigned short* A = (const unsigned short*)Av;
        int r  = tid >> 2;
        int kb = (tid & 3) * 8;
        #pragma unroll
        for (int kk = 0; kk < 8; kk++){
            int k = kb + kk*32;
            float v[8];
            load_bf16x8(A + (size_t)(m0 + r)*lda + koff + k, v);
            #pragma unroll
            for (int t = 0; t < 8; t++) As[k + t][r] = v[t];
        }
    } else {
        const float* A = (const float*)Av;
        int r  = tid >> 2;
        int kb = (tid & 3) * 4;
        #pragma unroll
        for (int kk = 0; kk < 16; kk++){
            int k = kb + kk*16;
            float4 v = *reinterpret_cast<const float4*>(A + (size_t)(m0 + r)*lda + k);
            As[k+0][r] = v.x; As[k+1][r] = v.y; As[k+2][r] = v.z; As[k+3][r] = v.w;
        }
    }
    __syncthreads();

    const int ti = tid & 15;
    const int tj = tid >> 4;
    float acc[4][NM];
    #pragma unroll
    for (int i = 0; i < 4; i++)
        #pragma unroll
        for (int j = 0; j < NM; j++) acc[i][j] = 0.f;

    const float* Bp = B + n0 + tj*NM;
    #pragma unroll 4
    for (int c = 0; c < 256; c++){
        float4 a = *reinterpret_cast<const float4*>(&As[c][ti*4]);
        float av[4] = {a.x, a.y, a.z, a.w};
        float bv[NM];
        if (NM == 4){
            float4 b4 = *reinterpret_cast<const float4*>(Bp + (size_t)c*ldb);
            bv[0] = b4.x; bv[1] = b4.y; bv[2] = b4.z; bv[3] = b4.w;
        } else {
            float2 b2 = *reinterpret_cast<const float2*>(Bp + (size_t)c*ldb);
            bv[0] = b2.x; bv[1] = b2.y;
        }
        #pragma unroll
        for (int i = 0; i < 4; i++)
            #pragma unroll
            for (int j = 0; j < NM; j++) acc[i][j] += av[i] * bv[j];
    }

    #pragma unroll
    for (int i = 0; i < 4; i++){
        int row = m0 + ti*4 + i;
        #pragma unroll
        for (int j = 0; j < NM; j++){
            int n = n0 + tj*NM + j;
            float bvv = bias[n];
            float v = acc[i][j] + (WSBIAS ? wsb[(size_t)row*8 + (n0 >> 5)]*bvv : bvv);
            if (RES) v += res[(size_t)row*256 + n];
            C[(size_t)row*ldc + n] = v;
        }
    }
}

// ---------------- coords: bezier center + softmax + pixel coords + valid-weight sums ----
template<int WANT>
__global__ __launch_bounds__(256) void coords_kernel(
    const float* __restrict__ ctrl, const float* __restrict__ pc,
    const float* __restrict__ oa,    // 4096 x 96: [0..63]=offsets, [64..95]=logits
    float* __restrict__ coords,      // per (m,h): 4 pts x {x,y,w}
    float* __restrict__ wsb,         // per (m,h): valid-weight sum
    const int* __restrict__ flag)
{
    if (*flag != WANT) return;
    const int m0 = blockIdx.x * 32;
    const int r  = threadIdx.x >> 3;
    const int h  = threadIdx.x & 7;
    const int m  = m0 + r;

    float cx[4], cy[4];
    #pragma unroll
    for (int i = 0; i < 4; i++){
        cx[i] = ctrl[(size_t)m*8 + i*2 + 0];
        cy[i] = ctrl[(size_t)m*8 + i*2 + 1];
    }
    float lox = pc[0], loy = pc[1];
    float spx = pc[3] - lox, spy = pc[4] - loy;
    float sx = 0.f, sy = 0.f;
    for (int k = 0; k < NKSAMP; k++){
        float t = (float)k / (float)(NKSAMP - 1);
        float u = 1.f - t;
        float c0 = u*u*u, c1 = 3.f*u*u*t, c2 = 3.f*u*t*t, c3 = t*t*t;
        float dx = c0*cx[0] + c1*cx[1] + c2*cx[2] + c3*cx[3];
        float dy = c0*cy[0] + c1*cy[1] + c2*cy[2] + c3*cy[3];
        float rx = fminf(fmaxf((dx - lox)/spx, 0.01f), 0.99f);
        float ry = fminf(fmaxf((dy - loy)/spy, 0.01f), 0.99f);
        sx += rx; sy += ry;
    }
    float cxp = (sx / (float)NKSAMP) * (float)WWF - 0.5f;
    float cyp = (sy / (float)NKSAMP) * (float)HHF - 0.5f;

    const float* row = oa + (size_t)m*96;
    float a0 = row[64 + h*4 + 0], a1 = row[64 + h*4 + 1];
    float a2 = row[64 + h*4 + 2], a3 = row[64 + h*4 + 3];
    float mx = fmaxf(fmaxf(a0, a1), fmaxf(a2, a3));
    float e0 = __expf(a0 - mx), e1 = __expf(a1 - mx);
    float e2 = __expf(a2 - mx), e3 = __expf(a3 - mx);
    float inv = 1.f / (e0 + e1 + e2 + e3);
    float wp[4] = {e0*inv, e1*inv, e2*inv, e3*inv};

    float* cp = coords + ((size_t)m*8 + h)*12;
    float wsum = 0.f;
    #pragma unroll
    for (int p = 0; p < 4; p++){
        float x = cxp + row[h*8 + p*2 + 0];
        float y = cyp + row[h*8 + p*2 + 1];
        cp[p*3 + 0] = x; cp[p*3 + 1] = y; cp[p*3 + 2] = wp[p];
        float fx = floorf(x), fy = floorf(y);
        int x0 = (int)fx, y0 = (int)fy;
        float wx = x - fx, wy = y - fy;
        bool vx0 = (unsigned)x0 < WWF, vx1 = (unsigned)(x0+1) < WWF;
        bool vy0 = (unsigned)y0 < HHF, vy1 = (unsigned)(y0+1) < HHF;
        float w = wp[p];
        if (vy0 && vx0) wsum += w*(1.f-wx)*(1.f-wy);
        if (vy0 && vx1) wsum += w*wx*(1.f-wy);
        if (vy1 && vx0) wsum += w*(1.f-wx)*wy;
        if (vy1 && vx1) wsum += w*wx*wy;
    }
    wsb[(size_t)m*8 + h] = wsum;
}

// ---------------- gather: g[m][h*256+c] = sum over pts/corners of w * bev[...][c] ------
// 4 query rows per block; thread = (grp = rh slot 0..7, sub = 8-channel chunk 0..31).
template<bool TRANS, int WANT>
__global__ __launch_bounds__(256) void gather_kernel(
    const unsigned short* __restrict__ bevT,   // (B,HW,C) bf16 bits
    const float* __restrict__ bev,             // (B,C,HW) f32
    const float* __restrict__ coords,
    unsigned short* __restrict__ g,
    const int* __restrict__ flag)
{
    if (*flag != WANT) return;
    const int m0  = blockIdx.x * 4;
    const int b   = m0 >> 10;
    const int sub = threadIdx.x & 31;
    const int grp = threadIdx.x >> 5;

    for (int it = 0; it < 4; it++){
        int rh = it*8 + grp;
        int m  = m0 + (rh >> 3);
        int h  = rh & 7;
        float acc[8] = {0.f,0.f,0.f,0.f,0.f,0.f,0.f,0.f};
        const float* cp = coords + ((size_t)m*8 + h)*12;

        #pragma unroll
        for (int p = 0; p < 4; p++){
            float x = cp[p*3+0], y = cp[p*3+1], w = cp[p*3+2];
            float fx = floorf(x), fy = floorf(y);
            int x0 = (int)fx, y0 = (int)fy;
            float wx = x - fx, wy = y - fy;
            int   xs[4] = {x0, x0+1, x0,   x0+1};
            int   ys[4] = {y0, y0,   y0+1, y0+1};
            float ws4[4] = {w*(1.f-wx)*(1.f-wy), w*wx*(1.f-wy), w*(1.f-wx)*wy, w*wx*wy};
            #pragma unroll
            for (int cidx = 0; cidx < 4; cidx++){
                int xi = xs[cidx], yi = ys[cidx];
                if ((unsigned)xi < WWF && (unsigned)yi < HHF){
                    float wgt = ws4[cidx];
                    if (TRANS){
                        const unsigned short* rowp =
                            bevT + (((size_t)b*HWF + yi*WWF + xi)*DD + sub*8);
                        float v[8]; load_bf16x8(rowp, v);
                        #pragma unroll
                        for (int i = 0; i < 8; i++) acc[i] += wgt * v[i];
                    } else {
                        size_t base = ((size_t)b*DD + sub*8)*HWF + (size_t)(yi*WWF + xi);
                        #pragma unroll
                        for (int i = 0; i < 8; i++) acc[i] += wgt * bev[base + (size_t)i*HWF];
                    }
                }
            }
        }
        store_bf16x8(g + ((size_t)m*2048 + h*256 + sub*8), acc);
    }
}

// ---------------- round-4 monolith (kept as fallback / bf16-input safety net) ----------
template<typename T, bool TRANS, int WANT>
__global__ __launch_bounds__(256) void monolith_kernel(
    const T* __restrict__ qe, const T* __restrict__ ctrl,
    const T* __restrict__ bev, const bf16* __restrict__ bevT,
    const T* __restrict__ pc,
    const T* __restrict__ Wq, const T* __restrict__ bq,
    const T* __restrict__ Wval, const T* __restrict__ bval,
    const T* __restrict__ Woff, const T* __restrict__ boff,
    const T* __restrict__ Wattn, const T* __restrict__ battn,
    const T* __restrict__ Wdo, const T* __restrict__ bdo,
    const T* __restrict__ Wout, const T* __restrict__ bout,
    float* __restrict__ out, const int* __restrict__ flag)
{
    if (*flag != WANT) return;
    __shared__ float qe_s[4][256];
    __shared__ float q_s[4][256];
    __shared__ float oa_s[4][96];
    __shared__ float cen_s[4][2];
    __shared__ int   sx0_s[4][32];
    __shared__ int   sy0_s[4][32];
    __shared__ float swx_s[4][32];
    __shared__ float swy_s[4][32];
    __shared__ float sww_s[4][32];
    __shared__ float ws_s[4][8];
    __shared__ float g_s[4][2048];
    __shared__ float t_s[4][256];

    const int m0  = blockIdx.x * 4;
    const int b   = m0 >> 10;
    const int tid = threadIdx.x;

    for (int i = tid; i < 4*256; i += 256){
        int r = i >> 8, c = i & 255;
        qe_s[r][c] = ldf(qe, (size_t)(m0 + r)*256 + c);
    }
    if (tid < 4){
        int r = tid;
        float cx[4], cy[4];
        #pragma unroll
        for (int i = 0; i < 4; i++){
            cx[i] = ldf(ctrl, (size_t)(m0+r)*8 + i*2 + 0);
            cy[i] = ldf(ctrl, (size_t)(m0+r)*8 + i*2 + 1);
        }
        float lox = ldf(pc,0), loy = ldf(pc,1);
        float spx = ldf(pc,3) - lox, spy = ldf(pc,4) - loy;
        float sx = 0.f, sy = 0.f;
        for (int k = 0; k < NKSAMP; k++){
            float t = (float)k / (float)(NKSAMP - 1);
            float u = 1.f - t;
            float c0 = u*u*u, c1 = 3.f*u*u*t, c2 = 3.f*u*t*t, c3 = t*t*t;
            float dx = c0*cx[0] + c1*cx[1] + c2*cx[2] + c3*cx[3];
            float dy = c0*cy[0] + c1*cy[1] + c2*cy[2] + c3*cy[3];
            float rx = fminf(fmaxf((dx - lox)/spx, 0.01f), 0.99f);
            float ry = fminf(fmaxf((dy - loy)/spy, 0.01f), 0.99f);
            sx += rx; sy += ry;
        }
        cen_s[r][0] = sx / (float)NKSAMP;
        cen_s[r][1] = sy / (float)NKSAMP;
    }
    __syncthreads();

    {
        const int j = tid;
        float acc[4] = {0.f, 0.f, 0.f, 0.f};
        for (int c = 0; c < 256; c++){
            float w = ldf(Wq, (size_t)c*256 + j);
            #pragma unroll
            for (int r = 0; r < 4; r++) acc[r] += qe_s[r][c] * w;
        }
        float bias = ldf(bq, j);
        #pragma unroll
        for (int r = 0; r < 4; r++) q_s[r][j] = acc[r] + bias;
    }
    __syncthreads();

    for (int idx = tid; idx < 4*96; idx += 256){
        int r = idx / 96, col = idx % 96;
        float acc = 0.f;
        if (col < 64){
            for (int c = 0; c < 256; c++) acc += q_s[r][c] * ldf(Woff, (size_t)c*64 + col);
            acc += ldf(boff, col);
        } else {
            int cc = col - 64;
            for (int c = 0; c < 256; c++) acc += q_s[r][c] * ldf(Wattn, (size_t)c*32 + cc);
            acc += ldf(battn, cc);
        }
        oa_s[r][col] = acc;
    }
    __syncthreads();

    if (tid < 32){
        int r = tid >> 3, h = tid & 7;
        float a0 = oa_s[r][64 + h*4 + 0], a1 = oa_s[r][64 + h*4 + 1];
        float a2 = oa_s[r][64 + h*4 + 2], a3 = oa_s[r][64 + h*4 + 3];
        float mx = fmaxf(fmaxf(a0, a1), fmaxf(a2, a3));
        float e0 = __expf(a0 - mx), e1 = __expf(a1 - mx);
        float e2 = __expf(a2 - mx), e3 = __expf(a3 - mx);
        float inv = 1.f / (e0 + e1 + e2 + e3);
        float wp[4] = {e0*inv, e1*inv, e2*inv, e3*inv};
        float cxp = cen_s[r][0] * (float)WWF - 0.5f;
        float cyp = cen_s[r][1] * (float)HHF - 0.5f;
        float wsum = 0.f;
        #pragma unroll
        for (int p = 0; p < 4; p++){
            float x = cxp + oa_s[r][h*8 + p*2 + 0];
            float y = cyp + oa_s[r][h*8 + p*2 + 1];
            float fx = floorf(x), fy = floorf(y);
            int x0 = (int)fx, y0 = (int)fy;
            float wx = x - fx, wy = y - fy;
            int s = h*4 + p;
            sx0_s[r][s] = x0; sy0_s[r][s] = y0;
            swx_s[r][s] = wx; swy_s[r][s] = wy;
            sww_s[r][s] = wp[p];
            bool vx0 = (unsigned)x0 < WWF, vx1 = (unsigned)(x0+1) < WWF;
            bool vy0 = (unsigned)y0 < HHF, vy1 = (unsigned)(y0+1) < HHF;
            float w = wp[p];
            if (vy0 && vx0) wsum += w*(1.f-wx)*(1.f-wy);
            if (vy0 && vx1) wsum += w*wx*(1.f-wy);
            if (vy1 && vx0) wsum += w*(1.f-wx)*wy;
            if (vy1 && vx1) wsum += w*wx*wy;
        }
        ws_s[r][h] = wsum;
    }
    __syncthreads();

    {
        const int c = tid;
        const bf16* baseT = bevT + (size_t)b * HWF * DD;
        const T*    baseR = bev  + (size_t)b * DD * HWF;
        for (int r = 0; r < 4; r++){
            #pragma unroll
            for (int h = 0; h < 8; h++){
                float acc = 0.f;
                #pragma unroll
                for (int p = 0; p < 4; p++){
                    int s = h*4 + p;
                    int x0 = sx0_s[r][s], y0 = sy0_s[r][s];
                    float wx = swx_s[r][s], wy = swy_s[r][s], w = sww_s[r][s];
                    float w00 = w*(1.f-wx)*(1.f-wy);
                    float w01 = w*wx*(1.f-wy);
                    float w10 = w*(1.f-wx)*wy;
                    float w11 = w*wx*wy;
                    bool vy0 = (unsigned)y0 < HHF, vy1 = (unsigned)(y0+1) < HHF;
                    bool vx0 = (unsigned)x0 < WWF, vx1 = (unsigned)(x0+1) < WWF;
                    if (vy0){
                        int rowp = y0*WWF + x0;
                        if (vx0) acc += w00 * (TRANS ? __bfloat162float(baseT[(size_t)rowp*DD + c])
                                                     : ldf(baseR, (size_t)c*HWF + rowp));
                        if (vx1) acc += w01 * (TRANS ? __bfloat162float(baseT[(size_t)(rowp+1)*DD + c])
                                                     : ldf(baseR, (size_t)c*HWF + rowp+1));
                    }
                    if (vy1){
                        int rowp = (y0+1)*WWF + x0;
                        if (vx0) acc += w10 * (TRANS ? __bfloat162float(baseT[(size_t)rowp*DD + c])
                                                     : ldf(baseR, (size_t)c*HWF + rowp));
                        if (vx1) acc += w11 * (TRANS ? __bfloat162float(baseT[(size_t)(rowp+1)*DD + c])
                                                     : ldf(baseR, (size_t)c*HWF + rowp+1));
                    }
                }
                g_s[r][h*256 + c] = acc;
            }
        }
    }
    __syncthreads();

    {
        const int j = tid;
        const int h = j >> 5;
        float acc[4] = {0.f, 0.f, 0.f, 0.f};
        for (int c = 0; c < 256; c++){
            float w = ldf(Wval, (size_t)c*256 + j);
            #pragma unroll
            for (int r = 0; r < 4; r++) acc[r] += g_s[r][h*256 + c] * w;
        }
        float bv = ldf(bval, j);
        #pragma unroll
        for (int r = 0; r < 4; r++) t_s[r][j] = acc[r] + ws_s[r][h] * bv;
    }
    __syncthreads();

    {
        const int j = tid;
        float acc[4] = {0.f, 0.f, 0.f, 0.f};
        for (int c = 0; c < 256; c++){
            float w = ldf(Wdo, (size_t)c*256 + j);
            #pragma unroll
            for (int r = 0; r < 4; r++) acc[r] += t_s[r][c] * w;
        }
        __syncthreads();
        float bd = ldf(bdo, j);
        #pragma unroll
        for (int r = 0; r < 4; r++) t_s[r][j] = acc[r] + bd + q_s[r][j];
    }
    __syncthreads();

    {
        const int j = tid;
        float acc[4] = {0.f, 0.f, 0.f, 0.f};
        for (int c = 0; c < 256; c++){
            float w = ldf(Wout, (size_t)c*256 + j);
            #pragma unroll
            for (int r = 0; r < 4; r++) acc[r] += t_s[r][c] * w;
        }
        float bo = ldf(bout, j);
        #pragma unroll
        for (int r = 0; r < 4; r++)
            out[(size_t)(m0+r)*256 + j] = acc[r] + bo;
    }
}

template<typename T, bool TRANS, int WANT>
static void launch_monolith(void* const* d_in, const bf16* bevT, float* out,
                            const int* flag, hipStream_t stream)
{
    monolith_kernel<T, TRANS, WANT><<<dim3(BB*NN/4), 256, 0, stream>>>(
        (const T*)d_in[0], (const T*)d_in[1], (const T*)d_in[2], bevT,
        (const T*)d_in[4],
        (const T*)d_in[5], (const T*)d_in[6], (const T*)d_in[7], (const T*)d_in[8],
        (const T*)d_in[9], (const T*)d_in[10], (const T*)d_in[11], (const T*)d_in[12],
        (const T*)d_in[13], (const T*)d_in[14], (const T*)d_in[15], (const T*)d_in[16],
        out, flag);
}

extern "C" void kernel_launch(void* const* d_in, const int* in_sizes, int n_in,
                              void* d_out, int out_size, void* d_ws, size_t ws_size,
                              hipStream_t stream)
{
    (void)in_sizes; (void)n_in; (void)out_size;
    float* out = (float*)d_out;
    char*  ws  = (char*)d_ws;

    // workspace layout (all offsets 256B-aligned)
    const size_t OF_FLAG = 0;
    const size_t OF_QBUF = 256;
    const size_t OF_OA   = OF_QBUF + (size_t)4096*256*4;      //  4,194,560
    const size_t OF_CO   = OF_OA   + (size_t)4096*96*4;       //  5,767,424
    const size_t OF_WSB  = OF_CO   + (size_t)4096*8*48;       //  7,340,288
    const size_t OF_T1   = OF_WSB  + (size_t)4096*8*4;        //  7,471,360
    const size_t OF_T2   = OF_T1   + (size_t)4096*256*4;      // 11,665,664
    const size_t OF_G    = OF_T2   + (size_t)4096*256*4;      // 15,859,968
    const size_t OF_BT   = OF_G    + (size_t)4096*2048*2;     // 32,637,184
    const size_t NEED_A  = OF_BT + (size_t)BB*HWF*DD*2;       // 114,557,184
    const size_t NEED_R4 = 64 + (size_t)BB*HWF*DD*2;          //  81,920,064
    const size_t NEED_B  = OF_BT;                             //  32,637,184

    int*            flag   = (int*)(ws + OF_FLAG);
    float*          qbuf   = (float*)(ws + OF_QBUF);
    float*          oa     = (float*)(ws + OF_OA);
    float*          coords = (float*)(ws + OF_CO);
    float*          wsb    = (float*)(ws + OF_WSB);
    float*          t1     = (float*)(ws + OF_T1);
    float*          t2     = (float*)(ws + OF_T2);
    unsigned short* g      = (unsigned short*)(ws + OF_G);
    unsigned short* bevT   = (unsigned short*)(ws + OF_BT);

    const float* qe    = (const float*)d_in[0];
    const float* ctrl  = (const float*)d_in[1];
    const float* bev   = (const float*)d_in[2];
    const float* pc    = (const float*)d_in[4];
    const float* Wq    = (const float*)d_in[5];
    const float* bq    = (const float*)d_in[6];
    const float* Wval  = (const float*)d_in[7];
    const float* bval  = (const float*)d_in[8];
    const float* Woff  = (const float*)d_in[9];
    const float* boff  = (const float*)d_in[10];
    const float* Wattn = (const float*)d_in[11];
    const float* battn = (const float*)d_in[12];
    const float* Wdo   = (const float*)d_in[13];
    const float* bdo   = (const float*)d_in[14];
    const float* Wout  = (const float*)d_in[15];
    const float* bout  = (const float*)d_in[16];

    detect_kernel<<<1, 64, 0, stream>>>((const unsigned*)d_in[4], flag);

    if (ws_size >= NEED_A || ws_size >= NEED_B){
        const bool haveT = (ws_size >= NEED_A);

        // fp32 pipeline (flag==0)
        if (haveT)
            transpose_kernel<float, 0><<<dim3(HWF/32, DD/32, BB), 256, 0, stream>>>(
                bev, bevT, flag);

        // Q = qe @ Wq + bq
        gemm_kernel<64,4,false,false,false,false,0><<<dim3(4,64), 256, 0, stream>>>(
            qe, 256, Wq, 256, bq, nullptr, nullptr, qbuf, 256, flag);
        // oa[:,0:64] = Q @ Woff + boff
        gemm_kernel<64,4,false,false,false,false,0><<<dim3(1,64), 256, 0, stream>>>(
            qbuf, 256, Woff, 64, boff, nullptr, nullptr, oa, 96, flag);
        // oa[:,64:96] = Q @ Wattn + battn
        gemm_kernel<32,2,false,false,false,false,0><<<dim3(1,64), 256, 0, stream>>>(
            qbuf, 256, Wattn, 32, battn, nullptr, nullptr, oa + 64, 96, flag);
        // coords / softmax / wsb
        coords_kernel<0><<<dim3(128), 256, 0, stream>>>(ctrl, pc, oa, coords, wsb, flag);
        // gather
        if (haveT)
            gather_kernel<true, 0><<<dim3(1024), 256, 0, stream>>>(bevT, bev, coords, g, flag);
        else
            gather_kernel<false,0><<<dim3(1024), 256, 0, stream>>>(bevT, bev, coords, g, flag);
        // t1 = g(head-sliced) @ Wval + wsb*bval
        gemm_kernel<32,2,true,true,true,false,0><<<dim3(8,64), 256, 0, stream>>>(
            g, 2048, Wval, 256, bval, wsb, nullptr, t1, 256, flag);
        // t2 = t1 @ Wdo + bdo + qbuf
        gemm_kernel<64,4,false,false,false,true,0><<<dim3(4,64), 256, 0, stream>>>(
            t1, 256, Wdo, 256, bdo, nullptr, qbuf, t2, 256, flag);
        // out = t2 @ Wout + bout
        gemm_kernel<64,4,false,false,false,false,0><<<dim3(4,64), 256, 0, stream>>>(
            t2, 256, Wout, 256, bout, nullptr, nullptr, out, 256, flag);

        // bf16-input safety net (flag==1)
        if (haveT){
            transpose_kernel<bf16, 1><<<dim3(HWF/32, DD/32, BB), 256, 0, stream>>>(
                (const bf16*)d_in[2], bevT, flag);
            launch_monolith<bf16, true, 1>(d_in, (const bf16*)bevT, out, flag, stream);
        } else {
            launch_monolith<bf16, false, 1>(d_in, (const bf16*)bevT, out, flag, stream);
        }
    } else if (ws_size >= NEED_R4){
        // round-4 known-good path
        bf16* bevT4 = (bf16*)(ws + 64);
        transpose_kernel<float, 0><<<dim3(HWF/32, DD/32, BB), 256, 0, stream>>>(
            bev, (unsigned short*)bevT4, flag);
        transpose_kernel<bf16, 1><<<dim3(HWF/32, DD/32, BB), 256, 0, stream>>>(
            (const bf16*)d_in[2], (unsigned short*)bevT4, flag);
        launch_monolith<float, true, 0>(d_in, bevT4, out, flag, stream);
        launch_monolith<bf16,  true, 1>(d_in, bevT4, out, flag, stream);
    } else {
        launch_monolith<float, false, 0>(d_in, (const bf16*)ws, out, flag, stream);
        launch_monolith<bf16,  false, 1>(d_in, (const bf16*)ws, out, flag, stream);
    }
}

// Round 6
// 489.286 us; speedup vs baseline: 1.3025x; 1.0895x over previous
//
#include <hip/hip_runtime.h>
#include <hip/hip_bf16.h>

#define BB 4
#define NN 1024
#define DD 256
#define NHEADS 8
#define NPTS 4
#define NKSAMP 10
#define HHF 200
#define WWF 200
#define HWF (HHF*WWF)

typedef __hip_bfloat16 bf16;

__device__ __forceinline__ unsigned short f2bf(float f){
    unsigned u = __float_as_uint(f);
    return (unsigned short)((u + 0x7FFFu + ((u >> 16) & 1u)) >> 16);
}
__device__ __forceinline__ void load_bf16x8(const unsigned short* p, float* v){
    int4 t = *reinterpret_cast<const int4*>(p);
    unsigned q0 = (unsigned)t.x, q1 = (unsigned)t.y, q2 = (unsigned)t.z, q3 = (unsigned)t.w;
    v[0] = __uint_as_float(q0 << 16); v[1] = __uint_as_float(q0 & 0xFFFF0000u);
    v[2] = __uint_as_float(q1 << 16); v[3] = __uint_as_float(q1 & 0xFFFF0000u);
    v[4] = __uint_as_float(q2 << 16); v[5] = __uint_as_float(q2 & 0xFFFF0000u);
    v[6] = __uint_as_float(q3 << 16); v[7] = __uint_as_float(q3 & 0xFFFF0000u);
}
__device__ __forceinline__ void store_bf16x8(unsigned short* p, const float* v){
    int4 t;
    t.x = (int)((unsigned)f2bf(v[0]) | ((unsigned)f2bf(v[1]) << 16));
    t.y = (int)((unsigned)f2bf(v[2]) | ((unsigned)f2bf(v[3]) << 16));
    t.z = (int)((unsigned)f2bf(v[4]) | ((unsigned)f2bf(v[5]) << 16));
    t.w = (int)((unsigned)f2bf(v[6]) | ((unsigned)f2bf(v[7]) << 16));
    *reinterpret_cast<int4*>(p) = t;
}

// bev (B, C, HW) f32 -> bevT (B, HW, C) bf16 bits
__global__ __launch_bounds__(256) void transpose_kernel(const float* __restrict__ bev,
                                                        unsigned short* __restrict__ bevT){
    __shared__ unsigned short tile[32][33];
    int b  = blockIdx.z;
    int c0 = blockIdx.y * 32;
    int p0 = blockIdx.x * 32;
    int tx = threadIdx.x & 31;
    int ty = threadIdx.x >> 5;   // 0..7
    const float* src = bev + (size_t)b * DD * HWF;
    #pragma unroll
    for (int i = 0; i < 4; i++){
        int c = c0 + ty + i*8;
        tile[ty + i*8][tx] = f2bf(src[(size_t)c * HWF + p0 + tx]);
    }
    __syncthreads();
    unsigned short* dst = bevT + (size_t)b * HWF * DD;
    #pragma unroll
    for (int i = 0; i < 4; i++){
        int p = p0 + ty + i*8;
        dst[(size_t)p * DD + c0 + tx] = tile[tx][ty + i*8];
    }
}

// ---------------- tiled fp32 GEMM: C = A@B + bias (+ws*bias) (+res) ----------------
// A: M x K row-major (f32, or bf16-bits when ABF16), K = 256.
// tiles: 64 rows x NT cols; 256 threads = 16(ti rows) x 16(tj cols); micro 4 x NM.
template<int NT, int NM, bool ABF16, bool HEADSLICE, bool WSBIAS, bool RES>
__global__ __launch_bounds__(256) void gemm_kernel(
    const void* __restrict__ Av, int lda,
    const float* __restrict__ B, int ldb,
    const float* __restrict__ bias,
    const float* __restrict__ wsb,
    const float* __restrict__ res,
    float* __restrict__ C, int ldc)
{
    __shared__ float As[256][68];   // A^T staged; pitch 68 keeps float4 rows 16B-aligned
    const int n0  = blockIdx.x * NT;
    const int m0  = blockIdx.y * 64;
    const int tid = threadIdx.x;
    const int koff = HEADSLICE ? (n0 >> 5) * 256 : 0;

    if (ABF16){
        const unsigned short* A = (const unsigned short*)Av;
        int r  = tid >> 2;
        int kb = (tid & 3) * 8;
        #pragma unroll
        for (int kk = 0; kk < 8; kk++){
            int k = kb + kk*32;
            float v[8];
            load_bf16x8(A + (size_t)(m0 + r)*lda + koff + k, v);
            #pragma unroll
            for (int t = 0; t < 8; t++) As[k + t][r] = v[t];
        }
    } else {
        const float* A = (const float*)Av;
        int r  = tid >> 2;
        int kb = (tid & 3) * 4;
        #pragma unroll
        for (int kk = 0; kk < 16; kk++){
            int k = kb + kk*16;
            float4 v = *reinterpret_cast<const float4*>(A + (size_t)(m0 + r)*lda + k);
            As[k+0][r] = v.x; As[k+1][r] = v.y; As[k+2][r] = v.z; As[k+3][r] = v.w;
        }
    }
    __syncthreads();

    const int ti = tid & 15;
    const int tj = tid >> 4;
    float acc[4][NM];
    #pragma unroll
    for (int i = 0; i < 4; i++)
        #pragma unroll
        for (int j = 0; j < NM; j++) acc[i][j] = 0.f;

    const float* Bp = B + n0 + tj*NM;
    #pragma unroll 4
    for (int c = 0; c < 256; c++){
        float4 a = *reinterpret_cast<const float4*>(&As[c][ti*4]);
        float av[4] = {a.x, a.y, a.z, a.w};
        float bv[NM];
        if (NM == 4){
            float4 b4 = *reinterpret_cast<const float4*>(Bp + (size_t)c*ldb);
            bv[0] = b4.x; bv[1] = b4.y; bv[2] = b4.z; bv[3] = b4.w;
        } else {
            float2 b2 = *reinterpret_cast<const float2*>(Bp + (size_t)c*ldb);
            bv[0] = b2.x; bv[1] = b2.y;
        }
        #pragma unroll
        for (int i = 0; i < 4; i++)
            #pragma unroll
            for (int j = 0; j < NM; j++) acc[i][j] += av[i] * bv[j];
    }

    #pragma unroll
    for (int i = 0; i < 4; i++){
        int row = m0 + ti*4 + i;
        float wsv = WSBIAS ? wsb[(size_t)row*8 + (n0 >> 5)] : 0.f;
        if (NM == 4){
            float4 v; float* vp = (float*)&v;
            #pragma unroll
            for (int j = 0; j < 4; j++){
                int n = n0 + tj*4 + j;
                float bvv = bias[n];
                float t = acc[i][j] + (WSBIAS ? wsv*bvv : bvv);
                if (RES) t += res[(size_t)row*256 + n];
                vp[j] = t;
            }
            *reinterpret_cast<float4*>(&C[(size_t)row*ldc + n0 + tj*4]) = v;
        } else {
            float2 v; float* vp = (float*)&v;
            #pragma unroll
            for (int j = 0; j < 2; j++){
                int n = n0 + tj*2 + j;
                float bvv = bias[n];
                float t = acc[i][j] + (WSBIAS ? wsv*bvv : bvv);
                if (RES) t += res[(size_t)row*256 + n];
                vp[j] = t;
            }
            *reinterpret_cast<float2*>(&C[(size_t)row*ldc + n0 + tj*2]) = v;
        }
    }
}

// ---------------- oa GEMM (64 rows x [64 off | 32 attn]) + coords fused in epilogue ---
__global__ __launch_bounds__(256) void oacoords_kernel(
    const float* __restrict__ Q, const float* __restrict__ ctrl, const float* __restrict__ pc,
    const float* __restrict__ Woff, const float* __restrict__ boff,
    const float* __restrict__ Wattn, const float* __restrict__ battn,
    float* __restrict__ coords,      // per (m,h): 4 pts x {x,y,w}
    float* __restrict__ wsb)         // per (m,h): valid-weight sum
{
    __shared__ __align__(16) char smem[256*68*4];      // As, then reused as oaS
    float (*As)[68] = (float(*)[68])smem;
    __shared__ float cen_s[64][2];
    const int m0  = blockIdx.x * 64;
    const int tid = threadIdx.x;

    {   // stage A^T (Q rows m0..m0+63)
        int r  = tid >> 2;
        int kb = (tid & 3) * 4;
        #pragma unroll
        for (int kk = 0; kk < 16; kk++){
            int k = kb + kk*16;
            float4 v = *reinterpret_cast<const float4*>(Q + (size_t)(m0 + r)*256 + k);
            As[k+0][r] = v.x; As[k+1][r] = v.y; As[k+2][r] = v.z; As[k+3][r] = v.w;
        }
    }
    if (tid < 64){   // bezier centers (independent of As)
        int m = m0 + tid;
        float cx[4], cy[4];
        #pragma unroll
        for (int i = 0; i < 4; i++){
            cx[i] = ctrl[(size_t)m*8 + i*2 + 0];
            cy[i] = ctrl[(size_t)m*8 + i*2 + 1];
        }
        float lox = pc[0], loy = pc[1];
        float spx = pc[3] - lox, spy = pc[4] - loy;
        float sx = 0.f, sy = 0.f;
        for (int k = 0; k < NKSAMP; k++){
            float t = (float)k / (float)(NKSAMP - 1);
            float u = 1.f - t;
            float c0 = u*u*u, c1 = 3.f*u*u*t, c2 = 3.f*u*t*t, c3 = t*t*t;
            float dx = c0*cx[0] + c1*cx[1] + c2*cx[2] + c3*cx[3];
            float dy = c0*cy[0] + c1*cy[1] + c2*cy[2] + c3*cy[3];
            float rx = fminf(fmaxf((dx - lox)/spx, 0.01f), 0.99f);
            float ry = fminf(fmaxf((dy - loy)/spy, 0.01f), 0.99f);
            sx += rx; sy += ry;
        }
        cen_s[tid][0] = (sx / (float)NKSAMP) * (float)WWF - 0.5f;
        cen_s[tid][1] = (sy / (float)NKSAMP) * (float)HHF - 0.5f;
    }
    __syncthreads();

    const int ti = tid & 15;
    const int tj = tid >> 4;
    float ao[4][4], aa[4][2];
    #pragma unroll
    for (int i = 0; i < 4; i++){
        #pragma unroll
        for (int j = 0; j < 4; j++) ao[i][j] = 0.f;
        aa[i][0] = 0.f; aa[i][1] = 0.f;
    }
    #pragma unroll 4
    for (int c = 0; c < 256; c++){
        float4 a = *reinterpret_cast<const float4*>(&As[c][ti*4]);
        float av[4] = {a.x, a.y, a.z, a.w};
        float4 bo = *reinterpret_cast<const float4*>(Woff + (size_t)c*64 + tj*4);
        float2 ba = *reinterpret_cast<const float2*>(Wattn + (size_t)c*32 + tj*2);
        #pragma unroll
        for (int i = 0; i < 4; i++){
            ao[i][0] += av[i]*bo.x; ao[i][1] += av[i]*bo.y;
            ao[i][2] += av[i]*bo.z; ao[i][3] += av[i]*bo.w;
            aa[i][0] += av[i]*ba.x; aa[i][1] += av[i]*ba.y;
        }
    }
    __syncthreads();                 // As fully consumed
    float* oaS = (float*)smem;       // 64 x 96, reuse As storage
    #pragma unroll
    for (int i = 0; i < 4; i++){
        int r = ti*4 + i;
        #pragma unroll
        for (int j = 0; j < 4; j++) oaS[r*96 + tj*4 + j] = ao[i][j] + boff[tj*4 + j];
        oaS[r*96 + 64 + tj*2 + 0] = aa[i][0] + battn[tj*2 + 0];
        oaS[r*96 + 64 + tj*2 + 1] = aa[i][1] + battn[tj*2 + 1];
    }
    __syncthreads();

    for (int idx = tid; idx < 512; idx += 256){
        int r = idx >> 3, h = idx & 7;
        int m = m0 + r;
        const float* row = oaS + r*96;
        float a0 = row[64 + h*4 + 0], a1 = row[64 + h*4 + 1];
        float a2 = row[64 + h*4 + 2], a3 = row[64 + h*4 + 3];
        float mx = fmaxf(fmaxf(a0, a1), fmaxf(a2, a3));
        float e0 = __expf(a0 - mx), e1 = __expf(a1 - mx);
        float e2 = __expf(a2 - mx), e3 = __expf(a3 - mx);
        float inv = 1.f / (e0 + e1 + e2 + e3);
        float wp[4] = {e0*inv, e1*inv, e2*inv, e3*inv};
        float cxp = cen_s[r][0], cyp = cen_s[r][1];
        float* cp = coords + ((size_t)m*8 + h)*12;
        float wsum = 0.f;
        #pragma unroll
        for (int p = 0; p < 4; p++){
            float x = cxp + row[h*8 + p*2 + 0];
            float y = cyp + row[h*8 + p*2 + 1];
            cp[p*3 + 0] = x; cp[p*3 + 1] = y; cp[p*3 + 2] = wp[p];
            float fx = floorf(x), fy = floorf(y);
            int x0 = (int)fx, y0 = (int)fy;
            float wx = x - fx, wy = y - fy;
            bool vx0 = (unsigned)x0 < WWF, vx1 = (unsigned)(x0+1) < WWF;
            bool vy0 = (unsigned)y0 < HHF, vy1 = (unsigned)(y0+1) < HHF;
            float w = wp[p];
            if (vy0 && vx0) wsum += w*(1.f-wx)*(1.f-wy);
            if (vy0 && vx1) wsum += w*wx*(1.f-wy);
            if (vy1 && vx0) wsum += w*(1.f-wx)*wy;
            if (vy1 && vx1) wsum += w*wx*wy;
        }
        wsb[(size_t)m*8 + h] = wsum;
    }
}

// ---------------- gather: g[m][h*256+c] = sum over pts/corners of w * bev[...][c] ------
template<bool TRANS>
__global__ __launch_bounds__(256) void gather_kernel(
    const unsigned short* __restrict__ bevT,   // (B,HW,C) bf16 bits
    const float* __restrict__ bev,             // (B,C,HW) f32
    const float* __restrict__ coords,
    unsigned short* __restrict__ g)
{
    const int m0  = blockIdx.x * 4;
    const int b   = m0 >> 10;
    const int sub = threadIdx.x & 31;
    const int grp = threadIdx.x >> 5;

    for (int it = 0; it < 4; it++){
        int rh = it*8 + grp;
        int m  = m0 + (rh >> 3);
        int h  = rh & 7;
        float acc[8] = {0.f,0.f,0.f,0.f,0.f,0.f,0.f,0.f};
        const float* cp = coords + ((size_t)m*8 + h)*12;

        #pragma unroll
        for (int p = 0; p < 4; p++){
            float x = cp[p*3+0], y = cp[p*3+1], w = cp[p*3+2];
            float fx = floorf(x), fy = floorf(y);
            int x0 = (int)fx, y0 = (int)fy;
            float wx = x - fx, wy = y - fy;
            int   xs[4]  = {x0, x0+1, x0,   x0+1};
            int   ys[4]  = {y0, y0,   y0+1, y0+1};
            float ws4[4] = {w*(1.f-wx)*(1.f-wy), w*wx*(1.f-wy), w*(1.f-wx)*wy, w*wx*wy};
            #pragma unroll
            for (int cidx = 0; cidx < 4; cidx++){
                int xi = xs[cidx], yi = ys[cidx];
                if ((unsigned)xi < WWF && (unsigned)yi < HHF){
                    float wgt = ws4[cidx];
                    if (TRANS){
                        const unsigned short* rowp =
                            bevT + (((size_t)b*HWF + yi*WWF + xi)*DD + sub*8);
                        float v[8]; load_bf16x8(rowp, v);
                        #pragma unroll
                        for (int i = 0; i < 8; i++) acc[i] += wgt * v[i];
                    } else {
                        size_t base = ((size_t)b*DD + sub*8)*HWF + (size_t)(yi*WWF + xi);
                        #pragma unroll
                        for (int i = 0; i < 8; i++) acc[i] += wgt * bev[base + (size_t)i*HWF];
                    }
                }
            }
        }
        store_bf16x8(g + ((size_t)m*2048 + h*256 + sub*8), acc);
    }
}

extern "C" void kernel_launch(void* const* d_in, const int* in_sizes, int n_in,
                              void* d_out, int out_size, void* d_ws, size_t ws_size,
                              hipStream_t stream)
{
    (void)in_sizes; (void)n_in; (void)out_size;
    float* out = (float*)d_out;
    char*  ws  = (char*)d_ws;

    // workspace layout (256B-aligned offsets); bevT last so the fallback tier works
    const size_t OF_QBUF = 0;
    const size_t OF_CO   = OF_QBUF + (size_t)4096*256*4;      //  4,194,304
    const size_t OF_WSB  = OF_CO   + (size_t)4096*8*48;       //  5,767,168
    const size_t OF_T1   = OF_WSB  + (size_t)4096*8*4;        //  5,898,240
    const size_t OF_T2   = OF_T1   + (size_t)4096*256*4;      // 10,092,544
    const size_t OF_G    = OF_T2   + (size_t)4096*256*4;      // 14,286,848
    const size_t OF_BT   = OF_G    + (size_t)4096*2048*2;     // 31,064,064
    const size_t NEED    = OF_BT   + (size_t)BB*HWF*DD*2;     // 112,984,064

    float*          qbuf   = (float*)(ws + OF_QBUF);
    float*          coords = (float*)(ws + OF_CO);
    float*          wsb    = (float*)(ws + OF_WSB);
    float*          t1     = (float*)(ws + OF_T1);
    float*          t2     = (float*)(ws + OF_T2);
    unsigned short* g      = (unsigned short*)(ws + OF_G);
    unsigned short* bevT   = (unsigned short*)(ws + OF_BT);

    const float* qe    = (const float*)d_in[0];
    const float* ctrl  = (const float*)d_in[1];
    const float* bev   = (const float*)d_in[2];
    const float* pc    = (const float*)d_in[4];
    const float* Wq    = (const float*)d_in[5];
    const float* bq    = (const float*)d_in[6];
    const float* Wval  = (const float*)d_in[7];
    const float* bval  = (const float*)d_in[8];
    const float* Woff  = (const float*)d_in[9];
    const float* boff  = (const float*)d_in[10];
    const float* Wattn = (const float*)d_in[11];
    const float* battn = (const float*)d_in[12];
    const float* Wdo   = (const float*)d_in[13];
    const float* bdo   = (const float*)d_in[14];
    const float* Wout  = (const float*)d_in[15];
    const float* bout  = (const float*)d_in[16];

    const bool haveT = (ws_size >= NEED);

    if (haveT)
        transpose_kernel<<<dim3(HWF/32, DD/32, BB), 256, 0, stream>>>(bev, bevT);

    // q = qe @ Wq + bq
    gemm_kernel<64,4,false,false,false,false><<<dim3(4,64), 256, 0, stream>>>(
        qe, 256, Wq, 256, bq, nullptr, nullptr, qbuf, 256);
    // oa = q @ [Woff|Wattn] + bias  -> coords/softmax/wsb (oa stays in LDS)
    oacoords_kernel<<<dim3(64), 256, 0, stream>>>(
        qbuf, ctrl, pc, Woff, boff, Wattn, battn, coords, wsb);
    // gather
    if (haveT)
        gather_kernel<true ><<<dim3(1024), 256, 0, stream>>>(bevT, bev, coords, g);
    else
        gather_kernel<false><<<dim3(1024), 256, 0, stream>>>(bevT, bev, coords, g);
    // t1 = g(head-sliced) @ Wval + wsb*bval
    gemm_kernel<32,2,true,true,true,false><<<dim3(8,64), 256, 0, stream>>>(
        g, 2048, Wval, 256, bval, wsb, nullptr, t1, 256);
    // t2 = t1 @ Wdo + bdo + qbuf
    gemm_kernel<64,4,false,false,false,true><<<dim3(4,64), 256, 0, stream>>>(
        t1, 256, Wdo, 256, bdo, nullptr, qbuf, t2, 256);
    // out = t2 @ Wout + bout
    gemm_kernel<64,4,false,false,false,false><<<dim3(4,64), 256, 0, stream>>>(
        t2, 256, Wout, 256, bout, nullptr, nullptr, out, 256);
}